// Round 8
// baseline (94.844 us; speedup 1.0000x reference)
//
#include <hip/hip_runtime.h>
#include <math.h>

constexpr int Bn = 8, Nn = 4096, Cn = 1024, Hn = 256, Kn = 3;
constexpr float EPS = 1e-5f;
constexpr int ROWS = 64;                 // rows per colsum block
constexpr int NBLK = Nn / ROWS;          // 64 partial blocks per batch
constexpr int STRIP = 16;                // rows per conv wave

typedef float v4f __attribute__((ext_vector_type(4)));

// ---------------- kernel 1: partial column sums over N (no atomics) ----------
__global__ __launch_bounds__(256) void k_colsum(const float* __restrict__ x,
                                                float* __restrict__ partial) {
    int blk = blockIdx.x;                 // Bn * NBLK = 512 blocks
    int b  = blk / NBLK;
    int n0 = (blk % NBLK) * ROWS;
    int c  = threadIdx.x * 4;
    const float* p = x + ((size_t)b * Nn + n0) * Cn + c;
    float4 acc = make_float4(0.f, 0.f, 0.f, 0.f);
    #pragma unroll 8
    for (int r = 0; r < ROWS; ++r) {
        float4 v = *reinterpret_cast<const float4*>(p + (size_t)r * Cn);
        acc.x += v.x; acc.y += v.y; acc.z += v.z; acc.w += v.w;
    }
    *reinterpret_cast<float4*>(partial + (size_t)blk * Cn + c) = acc;
}

// ---- kernel 2 (fused MLP): ctx-reduce -> gelu(ctx@W1+b1) -> h@W2+b2 --------
// 32 blocks = 8 batches x 4 output-quarters; 1024 threads. Short chains:
// A = 32 indep coalesced loads/thread; B = 4-way split-K (256 fmaf);
// C = 4 indep chains over coalesced W2. All redundancy (ctx, h per quarter)
// is L2/L3-resident and cheap.
__global__ __launch_bounds__(1024) void k_mlp(const float* __restrict__ partial,
                                              const float* __restrict__ W1,
                                              const float* __restrict__ b1,
                                              const float* __restrict__ W2,
                                              const float* __restrict__ b2,
                                              float* __restrict__ kern) {
    int b = blockIdx.x >> 2;
    int q = blockIdx.x & 3;
    int t = threadIdx.x;

    __shared__ float ctx[Cn];
    __shared__ float red[4][256];
    __shared__ float hs[Hn];

    // phase A: thread t reduces channel t over NBLK partial rows
    const float invN = 1.0f / (float)Nn;
    const float* pp = partial + (size_t)b * NBLK * Cn;
    float a0 = 0.f, a1 = 0.f;
    #pragma unroll 8
    for (int p = 0; p < NBLK; p += 2) {
        a0 += pp[(size_t)p * Cn + t];
        a1 += pp[(size_t)(p + 1) * Cn + t];
    }
    ctx[t] = (a0 + a1) * invN;
    __syncthreads();

    // phase B: h = gelu(ctx @ W1 + b1), 4-way split-K, exact erf GELU
    int j = t & 255, ks = t >> 8;
    const float* w1 = W1 + j;
    int c0 = ks * 256;
    float acc = 0.f;
    #pragma unroll 8
    for (int cc = 0; cc < 256; ++cc)
        acc = fmaf(ctx[c0 + cc], w1[(size_t)(c0 + cc) * Hn], acc);
    red[ks][j] = acc;
    __syncthreads();
    if (t < 256) {
        float v = red[0][t] + red[1][t] + red[2][t] + red[3][t] + b1[t];
        hs[t] = 0.5f * v * (1.0f + erff(v * 0.70710678118654752440f));
    }
    __syncthreads();

    // phase C: this quarter's 768 outputs of h @ W2 + b2 (transposed [B][K][C])
    if (t < 768) {
        int m = q * 768 + t;
        const float* w2 = W2 + m;
        float s0 = 0.f, s1 = 0.f, s2 = 0.f, s3 = 0.f;
        #pragma unroll 4
        for (int jj = 0; jj < Hn; jj += 4) {
            s0 = fmaf(hs[jj],     w2[(size_t)jj       * (Cn * Kn)], s0);
            s1 = fmaf(hs[jj + 1], w2[(size_t)(jj + 1) * (Cn * Kn)], s1);
            s2 = fmaf(hs[jj + 2], w2[(size_t)(jj + 2) * (Cn * Kn)], s2);
            s3 = fmaf(hs[jj + 3], w2[(size_t)(jj + 3) * (Cn * Kn)], s3);
        }
        float val = (s0 + s1) + (s2 + s3) + b2[m];
        int c = m / Kn, k = m - c * Kn;
        kern[((size_t)b * Kn + k) * Cn + c] = val;
    }
}

// ---- kernel 3: conv + residual + LN; sliding window strip of 16; NT stores -
__global__ __launch_bounds__(256) void k_conv_ln(const float* __restrict__ x,
                                                 const float* __restrict__ kern,
                                                 const float* __restrict__ gamma,
                                                 const float* __restrict__ beta,
                                                 float* __restrict__ out) {
    int bid = blockIdx.x;                          // 512 blocks (divisible by 8)
    int nb8 = gridDim.x >> 3;
    int sb  = (bid & 7) * nb8 + (bid >> 3);        // bijective XCD chunk swizzle
    int strip = sb * 4 + (threadIdx.x >> 6);       // 2048 strips total
    int b  = strip >> 8;                           // 256 strips per batch
    int n0 = (strip & 255) * STRIP;
    int lane = threadIdx.x & 63;

    const float4* xb = reinterpret_cast<const float4*>(x + (size_t)b * Nn * Cn);
    v4f*          ob = reinterpret_cast<v4f*>(out + (size_t)b * Nn * Cn);
    const float4* kb = reinterpret_cast<const float4*>(kern + (size_t)b * Kn * Cn);
    const float4* g4  = reinterpret_cast<const float4*>(gamma);
    const float4* be4 = reinterpret_cast<const float4*>(beta);
    const float4 z4 = make_float4(0.f, 0.f, 0.f, 0.f);

    float4 k0[4], k1[4], k2[4], g[4], be[4];
    float4 xm[4], xc[4], xp[4];
    #pragma unroll
    for (int k = 0; k < 4; ++k) {
        int ci = lane + (k << 6);                  // float4 index within row
        k0[k] = kb[ci];
        k1[k] = kb[ci + 256];
        k2[k] = kb[ci + 512];
        g[k]  = g4[ci];
        be[k] = be4[ci];
        xm[k] = (n0 > 0) ? xb[(size_t)(n0 - 1) * 256 + ci] : z4;
        xc[k] = xb[(size_t)n0 * 256 + ci];
    }

    #pragma unroll
    for (int i = 0; i < STRIP; ++i) {
        int n = n0 + i;
        bool hasP = (n < Nn - 1);
        #pragma unroll
        for (int k = 0; k < 4; ++k) {
            int ci = lane + (k << 6);
            xp[k] = hasP ? xb[(size_t)(n + 1) * 256 + ci] : z4;
        }

        float4 y[4];
        float s = 0.f, s2 = 0.f;
        #pragma unroll
        for (int k = 0; k < 4; ++k) {
            float4 v;
            v.x = fmaf(k0[k].x, xm[k].x, fmaf(k1[k].x, xc[k].x, fmaf(k2[k].x, xp[k].x, xc[k].x)));
            v.y = fmaf(k0[k].y, xm[k].y, fmaf(k1[k].y, xc[k].y, fmaf(k2[k].y, xp[k].y, xc[k].y)));
            v.z = fmaf(k0[k].z, xm[k].z, fmaf(k1[k].z, xc[k].z, fmaf(k2[k].z, xp[k].z, xc[k].z)));
            v.w = fmaf(k0[k].w, xm[k].w, fmaf(k1[k].w, xc[k].w, fmaf(k2[k].w, xp[k].w, xc[k].w)));
            y[k] = v;
            s  += (v.x + v.y) + (v.z + v.w);
            s2 += fmaf(v.x, v.x, fmaf(v.y, v.y, fmaf(v.z, v.z, v.w * v.w)));
        }

        #pragma unroll
        for (int off = 1; off < 64; off <<= 1) {
            s  += __shfl_xor(s,  off, 64);
            s2 += __shfl_xor(s2, off, 64);
        }

        float mu   = s * (1.0f / (float)Cn);
        float var  = fmaf(-mu, mu, s2 * (1.0f / (float)Cn));
        float rstd = rsqrtf(var + EPS);

        #pragma unroll
        for (int k = 0; k < 4; ++k) {
            int ci = lane + (k << 6);
            float4 v = y[k];
            v4f o;
            o.x = fmaf((v.x - mu) * rstd, g[k].x, be[k].x);
            o.y = fmaf((v.y - mu) * rstd, g[k].y, be[k].y);
            o.z = fmaf((v.z - mu) * rstd, g[k].z, be[k].z);
            o.w = fmaf((v.w - mu) * rstd, g[k].w, be[k].w);
            __builtin_nontemporal_store(o, &ob[(size_t)n * 256 + ci]);
        }

        #pragma unroll
        for (int k = 0; k < 4; ++k) { xm[k] = xc[k]; xc[k] = xp[k]; }
    }
}

extern "C" void kernel_launch(void* const* d_in, const int* in_sizes, int n_in,
                              void* d_out, int out_size, void* d_ws, size_t ws_size,
                              hipStream_t stream) {
    const float* x     = (const float*)d_in[0];
    const float* W1    = (const float*)d_in[1];
    const float* b1    = (const float*)d_in[2];
    const float* W2    = (const float*)d_in[3];
    const float* b2    = (const float*)d_in[4];
    const float* gamma = (const float*)d_in[5];
    const float* beta  = (const float*)d_in[6];
    float* out = (float*)d_out;

    float* ws      = (float*)d_ws;
    float* partial = ws;                                  // 512*1024 floats (2 MB)
    float* kern    = partial + (size_t)Bn * NBLK * Cn;    // 24576 floats

    k_colsum<<<Bn * NBLK, 256, 0, stream>>>(x, partial);
    k_mlp<<<Bn * 4, 1024, 0, stream>>>(partial, W1, b1, W2, b2, kern);
    k_conv_ln<<<Bn * Nn / (4 * STRIP), 256, 0, stream>>>(x, kern, gamma, beta, out);
}